// Round 2
// baseline (381.468 us; speedup 1.0000x reference)
//
#include <hip/hip_runtime.h>
#include <hip/hip_bf16.h>
#include <stdint.h>

typedef __attribute__((ext_vector_type(8))) short short8;
typedef __attribute__((ext_vector_type(4))) float floatx4;

#define B_ 16
#define C_ 512
#define S_ 4096
#define D_ 16

__device__ __forceinline__ unsigned short f2bf(float f) {
    union { float f; unsigned int i; } v;
    v.f = f;
    unsigned int u = v.i;
    return (unsigned short)((u + 0x7FFFu + ((u >> 16) & 1u)) >> 16);
}
__device__ __forceinline__ unsigned int pack2bf(float lo, float hi) {
    __hip_bfloat162 h = __float22bfloat162_rn(make_float2(lo, hi));
    union { __hip_bfloat162 h; unsigned int u; } v;
    v.h = h;
    return v.u;
}
// 8 fp32 (two float4) -> short8 bf16 via packed cvt
__device__ __forceinline__ short8 cvt8p(float4 a, float4 b) {
    union { unsigned int u[4]; short8 s; } r;
    r.u[0] = pack2bf(a.x, a.y);
    r.u[1] = pack2bf(a.z, a.w);
    r.u[2] = pack2bf(b.x, b.y);
    r.u[3] = pack2bf(b.z, b.w);
    return r.s;
}

// async global->LDS, 16B per lane. LDS dest is wave-uniform base
// (HW adds lane*16); global src is per-lane.
__device__ __forceinline__ void gl16(const void* g, void* l) {
    __builtin_amdgcn_global_load_lds(
        (const __attribute__((address_space(1))) unsigned int*)g,
        (__attribute__((address_space(3))) unsigned int*)l, 16, 0, 0);
}

// ---------------------------------------------------------------------------
// Kernel 1: q,k projection as LDS-staged skinny GEMM.
// qkp[ks][row][n] fp32 partials, row = b*512+c, n<16 = q, n>=16 = k.
// Block = 64 rows x 32 cols, BK=64, 4 waves (wave w owns rows w*16..+15).
// K split NS ways (NS=8 main path).  Grid = 128*NS blocks.
// LDS fp32 tiles, padded pitch 68 words -> conflict-free reads/writes.
// COALESCED x loads: per instr, 4 rows x 256B contiguous (vs old 16B gather).
// Register-prefetch of tile kk+1 under compute of tile kk (T14 split).
// ---------------------------------------------------------------------------
#define QP 68   // qk LDS word pitch (64 data + 4 pad; keeps 16B alignment)

template <int NS>
__global__ __launch_bounds__(256) void qk_kernel(
    const float* __restrict__ x,
    const float* __restrict__ Wq,
    const float* __restrict__ bq,
    const float* __restrict__ Wk,
    const float* __restrict__ bk,
    float* __restrict__ qkp)   // [NS][8192][32]
{
    constexpr int KCH = S_ / NS;    // K chunk per split
    constexpr int NK  = KCH / 64;   // ksteps
    __shared__ float Xs[64 * QP];   // [row64][k64] padded
    __shared__ float Ws[32 * QP];   // [n32][k64]  rows 0-15 Wq, 16-31 Wk
    int tid  = threadIdx.x;
    int lane = tid & 63;
    int w    = tid >> 6;
    int rt = blockIdx.x & 127;      // row-tile (fast -> adjacent blocks share W)
    int ks = blockIdx.x >> 7;       // K-split index
    int r0 = rt * 64;
    int k0 = ks * KCH;
    int fm = lane & 15;
    int q8 = lane >> 4;

    int su = tid >> 4;              // staging row 0..15
    int sv = tid & 15;              // staging float4 col 0..15

    const float* xbase  = x  + (size_t)(r0 + su) * S_ + k0 + sv * 4;
    const float* wqbase = Wq + (size_t)su * S_ + k0 + sv * 4;
    const float* wkbase = Wk + (size_t)su * S_ + k0 + sv * 4;

    floatx4 accq = {0.f, 0.f, 0.f, 0.f};
    floatx4 acck = {0.f, 0.f, 0.f, 0.f};

    float4 xv[4], wv[2];
    // prologue: load tile 0
#pragma unroll
    for (int i = 0; i < 4; ++i)
        xv[i] = *(const float4*)(xbase + (size_t)16 * i * S_);
    wv[0] = *(const float4*)(wqbase);
    wv[1] = *(const float4*)(wkbase);

    for (int kk = 0; kk < NK; ++kk) {
        // write staged regs to LDS
#pragma unroll
        for (int i = 0; i < 4; ++i)
            *(float4*)(&Xs[(16 * i + su) * QP + sv * 4]) = xv[i];
        *(float4*)(&Ws[su * QP + sv * 4])        = wv[0];
        *(float4*)(&Ws[(16 + su) * QP + sv * 4]) = wv[1];
        __syncthreads();

        // prefetch next tile into regs (independent of LDS; overlaps compute)
        if (kk + 1 < NK) {
            int off = (kk + 1) * 64;
#pragma unroll
            for (int i = 0; i < 4; ++i)
                xv[i] = *(const float4*)(xbase + (size_t)16 * i * S_ + off);
            wv[0] = *(const float4*)(wqbase + off);
            wv[1] = *(const float4*)(wkbase + off);
        }

#pragma unroll
        for (int kc = 0; kc < 2; ++kc) {
            const float* xr  = &Xs[(w * 16 + fm) * QP + kc * 32 + q8 * 8];
            const float* wqr = &Ws[fm * QP + kc * 32 + q8 * 8];
            const float* wkr = &Ws[(16 + fm) * QP + kc * 32 + q8 * 8];
            short8 a   = cvt8p(*(const float4*)xr,  *(const float4*)(xr + 4));
            short8 bq8 = cvt8p(*(const float4*)wqr, *(const float4*)(wqr + 4));
            short8 bk8 = cvt8p(*(const float4*)wkr, *(const float4*)(wkr + 4));
            accq = __builtin_amdgcn_mfma_f32_16x16x32_bf16(a, bq8, accq, 0, 0, 0);
            acck = __builtin_amdgcn_mfma_f32_16x16x32_bf16(a, bk8, acck, 0, 0, 0);
        }
        __syncthreads();
    }

    float biasq = (ks == 0) ? bq[fm] : 0.f;
    float biask = (ks == 0) ? bk[fm] : 0.f;
    float* outp = qkp + (size_t)ks * 8192 * 32;
#pragma unroll
    for (int r = 0; r < 4; ++r) {
        int row = r0 + w * 16 + q8 * 4 + r;
        outp[(size_t)row * 32 + fm]      = accq[r] + biasq;
        outp[(size_t)row * 32 + 16 + fm] = acck[r] + biask;
    }
}

// ---------------------------------------------------------------------------
// Kernel 1b: reduce the NS K-split partials.  qred[row][n] = sum_ks qkp.
// ---------------------------------------------------------------------------
template <int NS>
__global__ __launch_bounds__(256) void reduce_kernel(
    const float* __restrict__ qkp, float* __restrict__ qred)
{
    int g = blockIdx.x * 256 + threadIdx.x;   // 65536 float4s per slice
    const float4* p = (const float4*)qkp + g;
    float4 r = p[0];
#pragma unroll
    for (int k = 1; k < NS; ++k) {
        float4 v = p[(size_t)k * 65536];
        r.x += v.x; r.y += v.y; r.z += v.z; r.w += v.w;
    }
    ((float4*)qred)[g] = r;
}

// ---------------------------------------------------------------------------
// Kernel 2: kq[b,i,o] = q[b,i].k[b,o]; softmax over b; write A transposed
// as bf16 Abf[b][o][i].  Block = 32i x 16o, 512 threads, grid (16,32).
// ---------------------------------------------------------------------------
__global__ __launch_bounds__(512) void softmax_kernel(
    const float* __restrict__ qred,       // [8192][32]
    unsigned short* __restrict__ Abf)     // [16][512][512] = [b][o][i]
{
    __shared__ float lq[B_][32][17];
    __shared__ float lk[B_][16][17];
    int i0 = blockIdx.x * 32;
    int o0 = blockIdx.y * 16;
    int tid = threadIdx.x;

    {
        int d = tid & 15, il = tid >> 4;   // il 0..31
#pragma unroll
        for (int b = 0; b < 16; ++b)
            lq[b][il][d] = qred[(size_t)(b * C_ + i0 + il) * 32 + d];
    }
    if (tid < 256) {
        int d = tid & 15, ol = tid >> 4;   // ol 0..15
#pragma unroll
        for (int b = 0; b < 16; ++b)
            lk[b][ol][d] = qred[(size_t)(b * C_ + o0 + ol) * 32 + 16 + d];
    }
    __syncthreads();

    int i = tid & 31;
    int o = tid >> 5;    // 0..15
    float v[16];
#pragma unroll
    for (int b = 0; b < 16; ++b) {
        float s = 0.f;
#pragma unroll
        for (int d = 0; d < 16; ++d) s += lq[b][i][d] * lk[b][o][d];
        v[b] = s;
    }
    float mx = v[0];
#pragma unroll
    for (int b = 1; b < 16; ++b) mx = fmaxf(mx, v[b]);
    float sum = 0.f;
#pragma unroll
    for (int b = 0; b < 16; ++b) { v[b] = __expf(v[b] - mx); sum += v[b]; }
    float inv = 1.0f / sum;
#pragma unroll
    for (int b = 0; b < 16; ++b)
        Abf[(size_t)(b * C_ + o0 + o) * C_ + i0 + i] = f2bf(v[b] * inv);
}

// ---------------------------------------------------------------------------
// Kernel 3: out[b][o][s] = sum_i Abf[b][o][i] * x[b][i][s]
// 128x128 tile, BK=64, 4 waves x 64x64, 8 K-steps.
//   A tile: [128][64] bf16 LINEAR staged via global_load_lds width-16 with
//           SOURCE-PRE-SWIZZLED columns (rule #21): LDS slot s of row r holds
//           global chunk s^(r&7); reads XOR the slot back.  Fixes the 16-way
//           bank conflict of the linear layout (rows are exactly 128 B).
//   X tile: transposed [s=128][i=64] bf16 (pitch 36 words), coalesced fp32
//           loads + pair-packed bf16 ds_write_b32 (4-way write, acceptable).
// MFMA accumulation order unchanged -> identical numerics.
// ---------------------------------------------------------------------------
#define XP 36   // Xt word pitch (mult of 4 for b128-aligned frag reads)

__global__ __launch_bounds__(256) void av_kernel(
    const unsigned short* __restrict__ Abf,  // [16][512][512] bf16
    const float* __restrict__ x,             // [16][512][4096] fp32
    float* __restrict__ out)                 // [16][512][4096] fp32
{
    __shared__ unsigned int At[128 * 32];  // row=o_local, 64 bf16 i, swizzled
    __shared__ unsigned int Xt[128 * XP];  // row=s_local, 64 bf16 i (pairs)
    int b  = blockIdx.z;
    int o0 = blockIdx.y * 128;
    int s0 = blockIdx.x * 128;
    int tid  = threadIdx.x;
    int lane = tid & 63;
    int w    = tid >> 6;
    int wm = (w >> 1) * 64;
    int wn = (w & 1) * 64;
    int fm = lane & 15;
    int q8 = lane >> 4;

    floatx4 acc[4][4];
#pragma unroll
    for (int a = 0; a < 4; ++a)
#pragma unroll
        for (int c = 0; c < 4; ++c) acc[a][c] = (floatx4){0.f, 0.f, 0.f, 0.f};

    const unsigned short* Ab = Abf + (size_t)b * C_ * C_;
    const float* xb = x + (size_t)b * C_ * S_;

    // A-stage addressing: lane l writes LDS slot (l&7) of row base+(l>>3);
    // slot s of row r must hold global 16B-chunk s^(r&7)  (r&7 == (l>>3)&7).
    int arow_l = lane >> 3;                          // 0..7
    int acol   = ((lane & 7) ^ (arow_l & 7)) * 8;    // pre-swizzled source col

    // X-stage addressing: thread t -> float4 col xc (s=4*xc), i-pair xip+8r.
    int xc  = tid >> 3;              // 0..31
    int xip = tid & 7;               // 0..7

    for (int kb = 0; kb < 8; ++kb) {
        int i0 = kb * 64;
        // ---- stage A via global_load_lds (source-pre-swizzled) ----
#pragma unroll
        for (int q = 0; q < 4; ++q) {
            const unsigned short* gp =
                Ab + (size_t)(o0 + w * 32 + q * 8 + arow_l) * C_ + i0 + acol;
            unsigned int* lp = At + (w * 32 + q * 8) * 32;  // wave-uniform
            gl16(gp, lp);
        }
        // ---- stage X transposed (coalesced loads, pair-packed writes) ----
#pragma unroll
        for (int r = 0; r < 4; ++r) {
            int ip = r * 8 + xip;                       // i-pair 0..31
            const float* x0 = xb + (size_t)(i0 + 2 * ip) * S_ + s0 + xc * 4;
            float4 va = *(const float4*)x0;
            float4 vb = *(const float4*)(x0 + S_);
            unsigned int* dst = &Xt[(xc * 4) * XP + ip];
            dst[0 * XP] = pack2bf(va.x, vb.x);
            dst[1 * XP] = pack2bf(va.y, vb.y);
            dst[2 * XP] = pack2bf(va.z, vb.z);
            dst[3 * XP] = pack2bf(va.w, vb.w);
        }
        __syncthreads();

#pragma unroll
        for (int kc = 0; kc < 2; ++kc) {
            short8 af[4], bfr[4];
#pragma unroll
            for (int t = 0; t < 4; ++t)
                af[t] = *(const short8*)(&At[(wm + t * 16 + fm) * 32 +
                                             (((kc * 4 + q8) ^ (fm & 7)) << 2)]);
#pragma unroll
            for (int t = 0; t < 4; ++t)
                bfr[t] = *(const short8*)(&Xt[(wn + t * 16 + fm) * XP + kc * 16 + q8 * 4]);
#pragma unroll
            for (int a = 0; a < 4; ++a)
#pragma unroll
                for (int c = 0; c < 4; ++c)
                    acc[a][c] = __builtin_amdgcn_mfma_f32_16x16x32_bf16(af[a], bfr[c], acc[a][c], 0, 0, 0);
        }
        __syncthreads();
    }

    float* ob = out + (size_t)b * C_ * S_;
#pragma unroll
    for (int a = 0; a < 4; ++a) {
        int orow = o0 + wm + a * 16 + q8 * 4;
#pragma unroll
        for (int c = 0; c < 4; ++c) {
            int sc = s0 + wn + c * 16 + fm;
#pragma unroll
            for (int r = 0; r < 4; ++r)
                ob[(size_t)(orow + r) * S_ + sc] = acc[a][c][r];
        }
    }
}

extern "C" void kernel_launch(void* const* d_in, const int* in_sizes, int n_in,
                              void* d_out, int out_size, void* d_ws, size_t ws_size,
                              hipStream_t stream) {
    const float* x  = (const float*)d_in[0];
    const float* Wq = (const float*)d_in[1];
    const float* bq = (const float*)d_in[2];
    const float* Wk = (const float*)d_in[3];
    const float* bk = (const float*)d_in[4];
    float* out = (float*)d_out;

    if (ws_size >= (size_t)17 * 1024 * 1024) {
        // 8-way K-split: qkp 8MB @0, qred 1MB @8M, Abf 8MB @9M
        float* qkp = (float*)d_ws;
        float* qred = (float*)((char*)d_ws + (size_t)8 * 1024 * 1024);
        unsigned short* Abf =
            (unsigned short*)((char*)d_ws + (size_t)9 * 1024 * 1024);
        qk_kernel<8><<<128 * 8, 256, 0, stream>>>(x, Wq, bq, Wk, bk, qkp);
        reduce_kernel<8><<<256, 256, 0, stream>>>(qkp, qred);
        softmax_kernel<<<dim3(16, 32), 512, 0, stream>>>(qred, Abf);
        av_kernel<<<dim3(32, 4, 16), 256, 0, stream>>>(Abf, x, out);
    } else {
        // fallback: 4-way K-split: qkp 4MB @0, qred 1MB @4M, Abf 8MB @5M
        float* qkp = (float*)d_ws;
        float* qred = (float*)((char*)d_ws + (size_t)4 * 1024 * 1024);
        unsigned short* Abf =
            (unsigned short*)((char*)d_ws + (size_t)5 * 1024 * 1024);
        qk_kernel<4><<<128 * 4, 256, 0, stream>>>(x, Wq, bq, Wk, bk, qkp);
        reduce_kernel<4><<<256, 256, 0, stream>>>(qkp, qred);
        softmax_kernel<<<dim3(16, 32), 512, 0, stream>>>(qred, Abf);
        av_kernel<<<dim3(32, 4, 16), 256, 0, stream>>>(Abf, x, out);
    }
}

// Round 3
// 308.231 us; speedup vs baseline: 1.2376x; 1.2376x over previous
//
#include <hip/hip_runtime.h>
#include <hip/hip_bf16.h>
#include <stdint.h>

typedef __attribute__((ext_vector_type(8))) short short8;
typedef __attribute__((ext_vector_type(4))) float floatx4;

#define B_ 16
#define C_ 512
#define S_ 4096
#define D_ 16

__device__ __forceinline__ unsigned short f2bf(float f) {
    union { float f; unsigned int i; } v;
    v.f = f;
    unsigned int u = v.i;
    return (unsigned short)((u + 0x7FFFu + ((u >> 16) & 1u)) >> 16);
}
__device__ __forceinline__ unsigned int pack2bf(float lo, float hi) {
    __hip_bfloat162 h = __float22bfloat162_rn(make_float2(lo, hi));
    union { __hip_bfloat162 h; unsigned int u; } v;
    v.h = h;
    return v.u;
}
// 8 fp32 (two float4) -> short8 bf16 via packed cvt
__device__ __forceinline__ short8 cvt8p(float4 a, float4 b) {
    union { unsigned int u[4]; short8 s; } r;
    r.u[0] = pack2bf(a.x, a.y);
    r.u[1] = pack2bf(a.z, a.w);
    r.u[2] = pack2bf(b.x, b.y);
    r.u[3] = pack2bf(b.z, b.w);
    return r.s;
}

// async global->LDS, 16B per lane. LDS dest is wave-uniform base
// (HW adds lane*16); global src is per-lane.
__device__ __forceinline__ void gl16(const void* g, void* l) {
    __builtin_amdgcn_global_load_lds(
        (const __attribute__((address_space(1))) unsigned int*)g,
        (__attribute__((address_space(3))) unsigned int*)l, 16, 0, 0);
}

// ---------------------------------------------------------------------------
// Kernel 1: q,k projection (round-1 streaming form — empirically <94 us;
// the LDS-staged variant regressed to 111 us: x has reuse factor 1 here,
// so staging is pure overhead and the barriers serialize HBM latency).
// qkp[ks][row][n] fp32, row=b*512+c, n<16 = q, n>=16 = k.
// One wave: 16 rows x 32 cols over K-chunk S_/NS.  NS=8 -> 4096 waves.
// ---------------------------------------------------------------------------
template <int NS>
__global__ __launch_bounds__(256) void qk_kernel(
    const float* __restrict__ x,
    const float* __restrict__ Wq,
    const float* __restrict__ bq,
    const float* __restrict__ Wk,
    const float* __restrict__ bk,
    float* __restrict__ qkp)   // [NS][8192][32]
{
    int lane = threadIdx.x & 63;
    int w    = threadIdx.x >> 6;
    int gw   = blockIdx.x * 4 + w;
    int row_tile = gw / NS;
    int ks       = gw % NS;
    int m  = lane & 15;
    int q8 = lane >> 4;
    int k0 = ks * (S_ / NS);

    const float* ax = x  + (size_t)(row_tile * 16 + m) * S_ + k0 + q8 * 8;
    const float* aq = Wq + (size_t)m * S_ + k0 + q8 * 8;
    const float* ak = Wk + (size_t)m * S_ + k0 + q8 * 8;

    floatx4 accq = {0.f, 0.f, 0.f, 0.f};
    floatx4 acck = {0.f, 0.f, 0.f, 0.f};
#pragma unroll 4
    for (int it = 0; it < S_ / NS / 32; ++it) {
        float4 xa = *(const float4*)(ax + it * 32);
        float4 xb2 = *(const float4*)(ax + it * 32 + 4);
        float4 qa = *(const float4*)(aq + it * 32);
        float4 qb = *(const float4*)(aq + it * 32 + 4);
        float4 ka = *(const float4*)(ak + it * 32);
        float4 kb2 = *(const float4*)(ak + it * 32 + 4);
        short8 a   = cvt8p(xa, xb2);
        short8 bq8 = cvt8p(qa, qb);
        short8 bk8 = cvt8p(ka, kb2);
        accq = __builtin_amdgcn_mfma_f32_16x16x32_bf16(a, bq8, accq, 0, 0, 0);
        acck = __builtin_amdgcn_mfma_f32_16x16x32_bf16(a, bk8, acck, 0, 0, 0);
    }
    float biasq = (ks == 0) ? bq[m] : 0.f;
    float biask = (ks == 0) ? bk[m] : 0.f;
    float* outp = qkp + (size_t)ks * 8192 * 32;
#pragma unroll
    for (int r = 0; r < 4; ++r) {
        int row = row_tile * 16 + q8 * 4 + r;
        outp[(size_t)row * 32 + m]      = accq[r] + biasq;
        outp[(size_t)row * 32 + 16 + m] = acck[r] + biask;
    }
}

// ---------------------------------------------------------------------------
// Kernel 1b: reduce the NS K-split partials.  qred[row][n] = sum_ks qkp.
// ---------------------------------------------------------------------------
template <int NS>
__global__ __launch_bounds__(256) void reduce_kernel(
    const float* __restrict__ qkp, float* __restrict__ qred)
{
    int g = blockIdx.x * 256 + threadIdx.x;   // 65536 float4s per slice
    const float4* p = (const float4*)qkp + g;
    float4 r = p[0];
#pragma unroll
    for (int k = 1; k < NS; ++k) {
        float4 v = p[(size_t)k * 65536];
        r.x += v.x; r.y += v.y; r.z += v.z; r.w += v.w;
    }
    ((float4*)qred)[g] = r;
}

// ---------------------------------------------------------------------------
// Kernel 2: kq[b,i,o] = q[b,i].k[b,o]; softmax over b; write A transposed
// as bf16 Abf[b][o][i].  Block = 32i x 16o, 512 threads, grid (16,32).
// ---------------------------------------------------------------------------
__global__ __launch_bounds__(512) void softmax_kernel(
    const float* __restrict__ qred,       // [8192][32]
    unsigned short* __restrict__ Abf)     // [16][512][512] = [b][o][i]
{
    __shared__ float lq[B_][32][17];
    __shared__ float lk[B_][16][17];
    int i0 = blockIdx.x * 32;
    int o0 = blockIdx.y * 16;
    int tid = threadIdx.x;

    {
        int d = tid & 15, il = tid >> 4;   // il 0..31
#pragma unroll
        for (int b = 0; b < 16; ++b)
            lq[b][il][d] = qred[(size_t)(b * C_ + i0 + il) * 32 + d];
    }
    if (tid < 256) {
        int d = tid & 15, ol = tid >> 4;   // ol 0..15
#pragma unroll
        for (int b = 0; b < 16; ++b)
            lk[b][ol][d] = qred[(size_t)(b * C_ + o0 + ol) * 32 + 16 + d];
    }
    __syncthreads();

    int i = tid & 31;
    int o = tid >> 5;    // 0..15
    float v[16];
#pragma unroll
    for (int b = 0; b < 16; ++b) {
        float s = 0.f;
#pragma unroll
        for (int d = 0; d < 16; ++d) s += lq[b][i][d] * lk[b][o][d];
        v[b] = s;
    }
    float mx = v[0];
#pragma unroll
    for (int b = 1; b < 16; ++b) mx = fmaxf(mx, v[b]);
    float sum = 0.f;
#pragma unroll
    for (int b = 0; b < 16; ++b) { v[b] = __expf(v[b] - mx); sum += v[b]; }
    float inv = 1.0f / sum;
#pragma unroll
    for (int b = 0; b < 16; ++b)
        Abf[(size_t)(b * C_ + o0 + o) * C_ + i0 + i] = f2bf(v[b] * inv);
}

// ---------------------------------------------------------------------------
// Kernel 3: out[b][o][s] = sum_i Abf[b][o][i] * x[b][i][s]
// 256(o) x 128(s) tile, BK=64, 8 waves (4 o-rows x 2 s-cols of 64x64),
// 512 threads, grid (32, 2, 16).  Halves the per-output X-transpose cost
// vs the 128x128 tile (2 o-tiles share each x column instead of 4).
//   A tile: [256][64] bf16 linear via global_load_lds width-16 with
//           source-pre-swizzled columns (slot s of row r holds chunk
//           s^(r&7)); reads XOR the slot back -> conflict-free.
//   X tile: transposed [s=128][i=64] bf16 (pitch 36 words), coalesced
//           fp32 loads (8 rows x 128B runs/instr) + pair-packed bf16
//           ds_write_b32 (4-way bank, acceptable).
// MFMA accumulation order unchanged -> identical numerics.
// ---------------------------------------------------------------------------
#define XP 36   // Xt word pitch (mult of 4 for b128-aligned frag reads)

__global__ __launch_bounds__(512) void av_kernel(
    const unsigned short* __restrict__ Abf,  // [16][512][512] bf16
    const float* __restrict__ x,             // [16][512][4096] fp32
    float* __restrict__ out)                 // [16][512][4096] fp32
{
    __shared__ unsigned int At[256 * 32];  // 32 KB, row=o_local, swizzled
    __shared__ unsigned int Xt[128 * XP];  // 18 KB, row=s_local, i-pairs
    int b  = blockIdx.z;
    int o0 = blockIdx.y * 256;
    int s0 = blockIdx.x * 128;
    int tid  = threadIdx.x;
    int lane = tid & 63;
    int w    = tid >> 6;         // 0..7
    int wm = (w >> 1) * 64;      // o sub-tile (4 rows of waves)
    int wn = (w & 1) * 64;       // s sub-tile (2 cols of waves)
    int fm = lane & 15;
    int q8 = lane >> 4;

    floatx4 acc[4][4];
#pragma unroll
    for (int a = 0; a < 4; ++a)
#pragma unroll
        for (int c = 0; c < 4; ++c) acc[a][c] = (floatx4){0.f, 0.f, 0.f, 0.f};

    const unsigned short* Ab = Abf + (size_t)b * C_ * C_;
    const float* xb = x + (size_t)b * C_ * S_;

    // A-stage: lane l writes LDS slot (l&7) of row base+(l>>3); slot s of
    // row r must hold global 16B-chunk s^(r&7).
    int arow_l = lane >> 3;                          // 0..7
    int acol   = ((lane & 7) ^ (arow_l & 7)) * 8;    // pre-swizzled src col

    // X-stage: thread -> s-quad xc, i-pair ip = xhalf*16 + r*8 + xip.
    int xc    = (tid >> 3) & 31;     // 0..31 (s = 4*xc..+3)
    int xip   = tid & 7;             // 0..7
    int xhalf = tid >> 8;            // 0/1

    for (int kb = 0; kb < 8; ++kb) {
        int i0 = kb * 64;
        // ---- stage A via global_load_lds (source-pre-swizzled) ----
#pragma unroll
        for (int q = 0; q < 4; ++q) {
            const unsigned short* gp =
                Ab + (size_t)(o0 + w * 32 + q * 8 + arow_l) * C_ + i0 + acol;
            unsigned int* lp = At + (w * 32 + q * 8) * 32;  // wave-uniform
            gl16(gp, lp);
        }
        // ---- stage X transposed (coalesced loads, pair-packed writes) ----
#pragma unroll
        for (int r = 0; r < 2; ++r) {
            int ip = xhalf * 16 + r * 8 + xip;          // i-pair 0..31
            const float* x0 = xb + (size_t)(i0 + 2 * ip) * S_ + s0 + xc * 4;
            float4 va = *(const float4*)x0;
            float4 vb = *(const float4*)(x0 + S_);
            unsigned int* dst = &Xt[(xc * 4) * XP + ip];
            dst[0 * XP] = pack2bf(va.x, vb.x);
            dst[1 * XP] = pack2bf(va.y, vb.y);
            dst[2 * XP] = pack2bf(va.z, vb.z);
            dst[3 * XP] = pack2bf(va.w, vb.w);
        }
        __syncthreads();

#pragma unroll
        for (int kc = 0; kc < 2; ++kc) {
            short8 af[4], bfr[4];
#pragma unroll
            for (int t = 0; t < 4; ++t)
                af[t] = *(const short8*)(&At[(wm + t * 16 + fm) * 32 +
                                             (((kc * 4 + q8) ^ (fm & 7)) << 2)]);
#pragma unroll
            for (int t = 0; t < 4; ++t)
                bfr[t] = *(const short8*)(&Xt[(wn + t * 16 + fm) * XP + kc * 16 + q8 * 4]);
#pragma unroll
            for (int a = 0; a < 4; ++a)
#pragma unroll
                for (int c = 0; c < 4; ++c)
                    acc[a][c] = __builtin_amdgcn_mfma_f32_16x16x32_bf16(af[a], bfr[c], acc[a][c], 0, 0, 0);
        }
        __syncthreads();
    }

    float* ob = out + (size_t)b * C_ * S_;
#pragma unroll
    for (int a = 0; a < 4; ++a) {
        int orow = o0 + wm + a * 16 + q8 * 4;
#pragma unroll
        for (int c = 0; c < 4; ++c) {
            int sc = s0 + wn + c * 16 + fm;
#pragma unroll
            for (int r = 0; r < 4; ++r)
                ob[(size_t)(orow + r) * S_ + sc] = acc[a][c][r];
        }
    }
}

extern "C" void kernel_launch(void* const* d_in, const int* in_sizes, int n_in,
                              void* d_out, int out_size, void* d_ws, size_t ws_size,
                              hipStream_t stream) {
    const float* x  = (const float*)d_in[0];
    const float* Wq = (const float*)d_in[1];
    const float* bq = (const float*)d_in[2];
    const float* Wk = (const float*)d_in[3];
    const float* bk = (const float*)d_in[4];
    float* out = (float*)d_out;

    if (ws_size >= (size_t)17 * 1024 * 1024) {
        // 8-way K-split: qkp 8MB @0, qred 1MB @8M, Abf 8MB @9M
        float* qkp = (float*)d_ws;
        float* qred = (float*)((char*)d_ws + (size_t)8 * 1024 * 1024);
        unsigned short* Abf =
            (unsigned short*)((char*)d_ws + (size_t)9 * 1024 * 1024);
        qk_kernel<8><<<1024, 256, 0, stream>>>(x, Wq, bq, Wk, bk, qkp);
        reduce_kernel<8><<<256, 256, 0, stream>>>(qkp, qred);
        softmax_kernel<<<dim3(16, 32), 512, 0, stream>>>(qred, Abf);
        av_kernel<<<dim3(32, 2, 16), 512, 0, stream>>>(Abf, x, out);
    } else {
        // fallback: 4-way K-split: qkp 4MB @0, qred 1MB @4M, Abf 8MB @5M
        float* qkp = (float*)d_ws;
        float* qred = (float*)((char*)d_ws + (size_t)4 * 1024 * 1024);
        unsigned short* Abf =
            (unsigned short*)((char*)d_ws + (size_t)5 * 1024 * 1024);
        qk_kernel<4><<<512, 256, 0, stream>>>(x, Wq, bq, Wk, bk, qkp);
        reduce_kernel<4><<<256, 256, 0, stream>>>(qkp, qred);
        softmax_kernel<<<dim3(16, 32), 512, 0, stream>>>(qred, Abf);
        av_kernel<<<dim3(32, 2, 16), 512, 0, stream>>>(Abf, x, out);
    }
}